// Round 4
// baseline (1061.331 us; speedup 1.0000x reference)
//
#include <hip/hip_runtime.h>
#include <stdint.h>

typedef uint32_t u32;
typedef uint64_t u64;
typedef uint16_t u16;

#define NCLS 81
#define TOPK 200
#define KEEPK 200
#define CONF_THR 0.01f
#define NMS_THR 0.45f
#define NB 32
#define NP 24564
#define NFLAT (NCLS * TOPK) /* 16200 */

// order-preserving map float -> u32 (ascending)
__device__ __forceinline__ u32 fkey(float f) {
  u32 u = __float_as_uint(f);
  return (u & 0x80000000u) ? ~u : (u | 0x80000000u);
}
__device__ __forceinline__ float unfkey(u32 k) {
  u32 u = (k & 0x80000000u) ? (k & 0x7FFFFFFFu) : ~k;
  return __uint_as_float(u);
}

// ---------------------------------------------------------------------------
// Kernel 1: per (b,c) top-200 selection + decode + greedy NMS
// ---------------------------------------------------------------------------
__global__ __launch_bounds__(256) void perclass_topk_nms(
    const float* __restrict__ loc, const float* __restrict__ conf,
    const float* __restrict__ prior, float* __restrict__ kept,
    float* __restrict__ cbox) {
  __shared__ u16 skey[NP];             // 49128 B: top 16 bits of score key
  __shared__ unsigned int hist[256];
  __shared__ u64 keys[256];            // (score_key<<32) | ~prior_idx
  __shared__ float bx0[TOPK], bx1[TOPK], bx2[TOPK], bx3[TOPK];
  __shared__ float barea[TOPK], bscore[TOPK];
  __shared__ unsigned char sup[TOPK], keepf[TOPK];
  __shared__ unsigned int s_sel, s_rem, s_cnt, s_cnt2;

  const int tid = threadIdx.x;
  const int nwg = NB * NCLS;  // 2592, divisible by 8
  int i0 = blockIdx.x;
  // XCD-aware swizzle: each XCD gets a contiguous bc chunk (classes of same b
  // share conf cache lines: 16 classes / 64B line)
  int bc = (i0 & 7) * (nwg / 8) + (i0 >> 3);
  const int b = bc / NCLS, c = bc % NCLS;
  const size_t keptBase = (size_t)bc * TOPK;

  if (c == 0) {  // background class: reference forces conf to -1 -> all zeros
    for (int k = tid; k < TOPK; k += 256) {
      kept[keptBase + k] = 0.f;
      float* bp = cbox + (keptBase + k) * 4;
      bp[0] = 0.f; bp[1] = 0.f; bp[2] = 0.f; bp[3] = 0.f;
    }
    return;
  }

  const float* confb = conf + (size_t)b * NP * NCLS + c;
  auto loadscore = [&](int p) -> float {
    float s = confb[(size_t)p * NCLS];
    return (s > CONF_THR) ? s : -1.0f;
  };

  for (int p = tid; p < NP; p += 256)
    skey[p] = (u16)(fkey(loadscore(p)) >> 16);
  __syncthreads();

  auto select_bin = [&](u32 Kin) {  // scan hist from top bin; all threads call
    if (tid == 0) {
      u32 rem = Kin;
      int bin = 255;
      for (; bin > 0; --bin) {
        u32 cnt = hist[bin];
        if (cnt >= rem) break;
        rem -= cnt;
      }
      s_sel = (u32)bin; s_rem = rem;
    }
    __syncthreads();
  };

  // ---- radix select passes 1-2 on 16-bit LDS keys ----
  u32 K = TOPK;
  hist[tid] = 0; __syncthreads();
  for (int p = tid; p < NP; p += 256) atomicAdd(&hist[skey[p] >> 8], 1u);
  __syncthreads();
  select_bin(K);
  u32 pfx16 = s_sel << 8; K = s_rem;

  hist[tid] = 0; __syncthreads();
  {
    u32 hb = pfx16 >> 8;
    for (int p = tid; p < NP; p += 256) {
      u16 v = skey[p];
      if ((u32)(v >> 8) == hb) atomicAdd(&hist[v & 255], 1u);
    }
  }
  __syncthreads();
  select_bin(K);
  pfx16 |= s_sel; K = s_rem;

  const u32 NEGK16 = fkey(-1.0f) >> 16;  // 0x407F: all "-1" scores
  const bool fillMode = (pfx16 == NEGK16);
  u32 T;
  if (!fillMode) {
    // ---- passes 3-4 on full keys, only elements matching the 16-bit prefix
    u32 pfull = pfx16 << 16;
    hist[tid] = 0; __syncthreads();
    for (int p = tid; p < NP; p += 256) {
      if ((u32)skey[p] == pfx16) {
        u32 kf = fkey(loadscore(p));
        atomicAdd(&hist[(kf >> 8) & 255], 1u);
      }
    }
    __syncthreads();
    select_bin(K);
    pfull |= s_sel << 8; K = s_rem;

    hist[tid] = 0; __syncthreads();
    for (int p = tid; p < NP; p += 256) {
      if ((u32)skey[p] == pfx16) {
        u32 kf = fkey(loadscore(p));
        if ((kf >> 8) == (pfull >> 8)) atomicAdd(&hist[kf & 255], 1u);
      }
    }
    __syncthreads();
    select_bin(K);
    T = pfull | s_sel; K = s_rem;
  } else {
    T = fkey(-1.0f);
  }

  // ---- gather: G strictly-greater + ties (lowest-index ties win via sort) --
  const u32 G = TOPK - K;  // exactly G elements have key > T
  keys[tid] = 0;           // pad key sorts last
  if (tid == 0) { s_cnt = 0; s_cnt2 = 0; }
  __syncthreads();
  for (int p = tid; p < NP; p += 256) {
    u32 v = skey[p];
    if (v > pfx16) {
      float s = loadscore(p);
      u32 slot = atomicAdd(&s_cnt, 1u);
      keys[slot] = ((u64)fkey(s) << 32) | (u32)(~(u32)p);
    } else if (!fillMode && v == pfx16) {
      float s = loadscore(p);
      u32 kf = fkey(s);
      if (kf > T) {
        u32 slot = atomicAdd(&s_cnt, 1u);
        keys[slot] = ((u64)kf << 32) | (u32)(~(u32)p);
      } else if (kf == T) {
        u32 t2 = atomicAdd(&s_cnt2, 1u);
        u32 slot = G + t2;
        if (slot < 256u) keys[slot] = ((u64)kf << 32) | (u32)(~(u32)p);
      }
    }
  }
  __syncthreads();
  if (fillMode) {  // fill with inert (-1, idx 0) entries (gated to 0 later)
    for (int k = (int)G + tid; k < TOPK; k += 256)
      keys[k] = ((u64)T << 32) | 0xFFFFFFFFull;
  }
  __syncthreads();

  // ---- bitonic sort, 256 elems, descending (score desc, prior idx asc) ----
  for (u32 kk = 2; kk <= 256; kk <<= 1) {
    for (u32 j = kk >> 1; j > 0; j >>= 1) {
      u32 ixj = (u32)tid ^ j;
      if (ixj > (u32)tid) {
        u64 a = keys[tid], bb = keys[ixj];
        bool asc = (tid & kk) != 0;
        if (asc ? (a > bb) : (a < bb)) { keys[tid] = bb; keys[ixj] = a; }
      }
      __syncthreads();
    }
  }

  // ---- decode the 200 candidate boxes ----
  if (tid < TOPK) {
    u64 e = keys[tid];
    float s = unfkey((u32)(e >> 32));
    int p = (int)(~(u32)e);
    const float* lp = loc + ((size_t)b * NP + p) * 4;
    const float* pp = prior + (size_t)p * 4;
    const float* vp = prior + (size_t)NP * 4 + (size_t)p * 4;
    float p0 = pp[0], p1 = pp[1], p2 = pp[2], p3 = pp[3];
    float pw = p2 - p0, ph = p3 - p1;
    float pcx = (p0 + p2) * 0.5f, pcy = (p1 + p3) * 0.5f;
    float cx = vp[0] * lp[0] * pw + pcx;
    float cy = vp[1] * lp[1] * ph + pcy;
    float w = expf(vp[2] * lp[2]) * pw;
    float h = expf(vp[3] * lp[3]) * ph;
    float x0 = cx - w * 0.5f, y0 = cy - h * 0.5f;
    float x1 = cx + w * 0.5f, y1 = cy + h * 0.5f;
    bx0[tid] = x0; bx1[tid] = y0; bx2[tid] = x1; bx3[tid] = y1;
    barea[tid] = fmaxf(x1 - x0, 0.f) * fmaxf(y1 - y0, 0.f);
    bscore[tid] = s;
    sup[tid] = 0;
    keepf[tid] = 0;
  }
  __syncthreads();

  // ---- greedy sequential NMS (reference fori_loop semantics) ----
  for (int i = 0; i < TOPK; ++i) {
    bool kept_i = (bscore[i] > CONF_THR) && (sup[i] == 0);
    __syncthreads();  // everyone read sup[i]/bscore[i] before writes
    if (kept_i) {
      if (tid < TOPK) {
        float xx1 = fmaxf(bx0[i], bx0[tid]);
        float yy1 = fmaxf(bx1[i], bx1[tid]);
        float xx2 = fminf(bx2[i], bx2[tid]);
        float yy2 = fminf(bx3[i], bx3[tid]);
        float inter = fmaxf(xx2 - xx1, 0.f) * fmaxf(yy2 - yy1, 0.f);
        float uni = barea[i] + barea[tid] - inter;
        float iou = inter / fmaxf(uni, 1e-10f);
        if (iou > NMS_THR) sup[tid] = 1;
      }
      if (tid == 0) keepf[i] = 1;
    }
    __syncthreads();
  }

  if (tid < TOPK) {
    kept[keptBase + tid] = keepf[tid] ? bscore[tid] : 0.f;
    float* bp = cbox + (keptBase + tid) * 4;
    bp[0] = bx0[tid]; bp[1] = bx1[tid]; bp[2] = bx2[tid]; bp[3] = bx3[tid];
  }
}

// ---------------------------------------------------------------------------
// Kernel 2: per-batch top-200 over C*TOPK kept scores -> output rows
// ---------------------------------------------------------------------------
__global__ __launch_bounds__(256) void final_topk(
    const float* __restrict__ kept, const float* __restrict__ cbox,
    float* __restrict__ out) {
  __shared__ unsigned int hist[256];
  __shared__ u64 keys[256];
  __shared__ unsigned int s_sel, s_rem, s_cnt, s_cnt2;

  const int tid = threadIdx.x;
  const int b = blockIdx.x;
  const float* sc = kept + (size_t)b * NFLAT;

  auto select_bin = [&](u32 Kin) {
    if (tid == 0) {
      u32 rem = Kin;
      int bin = 255;
      for (; bin > 0; --bin) {
        u32 cnt = hist[bin];
        if (cnt >= rem) break;
        rem -= cnt;
      }
      s_sel = (u32)bin; s_rem = rem;
    }
    __syncthreads();
  };

  u32 pfx = 0;
  u32 K = KEEPK;
  for (int shift = 24; shift >= 0; shift -= 8) {
    hist[tid] = 0; __syncthreads();
    u32 himask = (shift == 24) ? 0u : (0xFFFFFFFFu << (shift + 8));
    for (int p = tid; p < NFLAT; p += 256) {
      u32 kf = fkey(sc[p]);
      if ((kf & himask) == pfx) atomicAdd(&hist[(kf >> shift) & 255], 1u);
    }
    __syncthreads();
    select_bin(K);
    pfx |= s_sel << shift; K = s_rem;
  }

  const bool fill2 = (pfx == fkey(0.0f));  // boundary is a zero score
  const u32 G = KEEPK - K;
  keys[tid] = 0;
  if (tid == 0) { s_cnt = 0; s_cnt2 = 0; }
  __syncthreads();
  for (int p = tid; p < NFLAT; p += 256) {
    u32 kf = fkey(sc[p]);
    if (kf > pfx) {
      u32 slot = atomicAdd(&s_cnt, 1u);
      keys[slot] = ((u64)kf << 32) | (u32)(~(u32)p);
    } else if (!fill2 && kf == pfx) {
      u32 t2 = atomicAdd(&s_cnt2, 1u);
      u32 slot = G + t2;
      if (slot < 256u) keys[slot] = ((u64)kf << 32) | (u32)(~(u32)p);
    }
  }
  __syncthreads();
  if (fill2) {
    for (int k = (int)G + tid; k < KEEPK; k += 256)
      keys[k] = ((u64)pfx << 32) | 0xFFFFFFFFull;
  }
  __syncthreads();

  for (u32 kk = 2; kk <= 256; kk <<= 1) {
    for (u32 j = kk >> 1; j > 0; j >>= 1) {
      u32 ixj = (u32)tid ^ j;
      if (ixj > (u32)tid) {
        u64 a = keys[tid], bb = keys[ixj];
        bool asc = (tid & kk) != 0;
        if (asc ? (a > bb) : (a < bb)) { keys[tid] = bb; keys[ixj] = a; }
      }
      __syncthreads();
    }
  }

  if (tid < KEEPK) {
    u64 e = keys[tid];
    float s = unfkey((u32)(e >> 32));
    u32 fi = ~(u32)e;
    float r0 = 0.f, r1 = 0.f, r2 = 0.f, r3 = 0.f, r4 = 0.f, r5 = 0.f, r6 = 0.f;
    if (s > 0.f) {
      r0 = (float)b;
      r1 = (float)(fi / TOPK);
      r2 = s;
      const float* bp = cbox + ((size_t)b * NFLAT + fi) * 4;
      r3 = bp[0]; r4 = bp[1]; r5 = bp[2]; r6 = bp[3];
    }
    float* op = out + ((size_t)b * KEEPK + tid) * 7;
    op[0] = r0; op[1] = r1; op[2] = r2; op[3] = r3;
    op[4] = r4; op[5] = r5; op[6] = r6;
  }
}

extern "C" void kernel_launch(void* const* d_in, const int* in_sizes, int n_in,
                              void* d_out, int out_size, void* d_ws, size_t ws_size,
                              hipStream_t stream) {
  const float* loc = (const float*)d_in[0];
  const float* conf = (const float*)d_in[1];
  const float* prior = (const float*)d_in[2];
  float* out = (float*)d_out;

  float* kept = (float*)d_ws;                            // NB*NCLS*TOPK floats
  float* cbox = kept + (size_t)NB * NCLS * TOPK;         // NB*NCLS*TOPK*4 floats

  perclass_topk_nms<<<dim3(NB * NCLS), dim3(256), 0, stream>>>(loc, conf, prior,
                                                               kept, cbox);
  final_topk<<<dim3(NB), dim3(256), 0, stream>>>(kept, cbox, out);
}

// Round 7
// 610.695 us; speedup vs baseline: 1.7379x; 1.7379x over previous
//
#include <hip/hip_runtime.h>
#include <stdint.h>

typedef uint32_t u32;
typedef uint64_t u64;
typedef uint16_t u16;

#define NCLS 81
#define TOPK 200
#define KEEPK 200
#define CONF_THR 0.01f
#define NMS_THR 0.45f
#define NB 32
#define NP 24564
#define NP2 (NP / 2)
#define NFLAT (NCLS * TOPK) /* 16200 */
#define NPCHUNK 256
#define NCHUNK ((NP + NPCHUNK - 1) / NPCHUNK) /* 96 */

// order-preserving map float -> u32 (ascending)
__device__ __forceinline__ u32 fkey(float f) {
  u32 u = __float_as_uint(f);
  return (u & 0x80000000u) ? ~u : (u | 0x80000000u);
}
__device__ __forceinline__ float unfkey(u32 k) {
  u32 u = (k & 0x80000000u) ? (k & 0x7FFFFFFFu) : ~k;
  return __uint_as_float(u);
}

// fkey(-1.0f) = ~0xBF800000 = 0x407FFFFF; top 16 bits = 0x407F
#define NEGKEY 0x407FFFFFu
#define NEGK16 0x407Fu

// ---------------------------------------------------------------------------
// Kernel 0: coalesced conf read -> thresholded u16 keys, transposed [B][C][P]
// ---------------------------------------------------------------------------
__global__ __launch_bounds__(256) void build_keys(const float* __restrict__ conf,
                                                  u16* __restrict__ keys16) {
  __shared__ u16 tile[NCLS][NPCHUNK + 2];  // 81 x 258 u16 = 41796 B

  const int tid = threadIdx.x;
  const int blk = blockIdx.x;
  const int b = blk / NCHUNK, chunk = blk % NCHUNK;
  const int p0 = chunk * NPCHUNK;
  const int cnt = min(NPCHUNK, NP - p0);  // 256 or 244 (even)
  const int tot = cnt * NCLS;
  const float* src = conf + ((size_t)b * NP + p0) * NCLS;  // 16B-aligned

  for (int f4 = tid * 4; f4 < tot; f4 += 256 * 4) {
    if (f4 + 3 < tot) {
      float4 v = *reinterpret_cast<const float4*>(src + f4);
      float vv[4] = {v.x, v.y, v.z, v.w};
#pragma unroll
      for (int j = 0; j < 4; ++j) {
        int f = f4 + j;
        int pi = f / NCLS, c = f - pi * NCLS;
        float s = vv[j];
        s = (s > CONF_THR) ? s : -1.0f;
        tile[c][pi] = (u16)(fkey(s) >> 16);
      }
    } else {
      for (int f = f4; f < tot; ++f) {
        int pi = f / NCLS, c = f - pi * NCLS;
        float s = src[f];
        s = (s > CONF_THR) ? s : -1.0f;
        tile[c][pi] = (u16)(fkey(s) >> 16);
      }
    }
  }
  __syncthreads();

  const int halves = cnt >> 1;  // 128 or 122
  u32* dst32 = (u32*)keys16;
  if (halves == 128) {
    for (int i = tid; i < NCLS * 128; i += 256) {
      int c = i >> 7, w = i & 127;
      u32 lo = tile[c][2 * w], hi = tile[c][2 * w + 1];
      size_t row = ((size_t)b * NCLS + c) * NP + p0;
      dst32[row / 2 + w] = lo | (hi << 16);
    }
  } else {
    for (int i = tid; i < NCLS * halves; i += 256) {
      int c = i / halves, w = i - c * halves;
      u32 lo = tile[c][2 * w], hi = tile[c][2 * w + 1];
      size_t row = ((size_t)b * NCLS + c) * NP + p0;
      dst32[row / 2 + w] = lo | (hi << 16);
    }
  }
}

// ---------------------------------------------------------------------------
// Kernel 1 (fast): per (b,c) top-200 via coalesced key row + decode + NMS
// ---------------------------------------------------------------------------
__global__ __launch_bounds__(256) void perclass_v2(
    const float* __restrict__ loc, const float* __restrict__ conf,
    const float* __restrict__ prior, const u16* __restrict__ keys16,
    float* __restrict__ kept, float* __restrict__ cbox) {
  __shared__ u32 hist[256];
  __shared__ u64 keys[256];   // (fullkey<<32) | ~prior_idx
  __shared__ u64 buf3[512];   // pfx16-matching elements with full keys
  __shared__ float bx0[TOPK], bx1[TOPK], bx2[TOPK], bx3[TOPK], barea[TOPK];
  __shared__ unsigned char keepf[TOPK];
  __shared__ u32 s_sel, s_rem, s_cnt, s_cnt2, s_cnt3;

  const int tid = threadIdx.x;
  const int nwg = NB * NCLS;  // 2592
  int i0 = blockIdx.x;
  int bc = (i0 & 7) * (nwg / 8) + (i0 >> 3);  // XCD swizzle (bijective: 2592%8==0)
  const int b = bc / NCLS, c = bc % NCLS;
  const size_t keptBase = (size_t)bc * TOPK;

  if (c == 0) {  // background class
    for (int k = tid; k < TOPK; k += 256) {
      kept[keptBase + k] = 0.f;
      float* bp = cbox + (keptBase + k) * 4;
      bp[0] = 0.f; bp[1] = 0.f; bp[2] = 0.f; bp[3] = 0.f;
    }
    return;
  }

  const u32* krow32 = (const u32*)(keys16 + ((size_t)b * NCLS + c) * NP);
  const float* confb = conf + (size_t)b * NP * NCLS + c;
  auto loadscore = [&](int p) -> float {
    float s = confb[(size_t)p * NCLS];
    return (s > CONF_THR) ? s : -1.0f;
  };

  auto select_bin = [&](u32 Kin) {
    if (tid == 0) {
      u32 rem = Kin;
      int bin = 255;
      for (; bin > 0; --bin) {
        u32 cnt = hist[bin];
        if (cnt >= rem) break;
        rem -= cnt;
      }
      s_sel = (u32)bin; s_rem = rem;
    }
    __syncthreads();
  };

  // ---- pass 1: hi byte of 16-bit key ----
  u32 K = TOPK;
  hist[tid] = 0; __syncthreads();
  for (int i = tid; i < NP2; i += 256) {
    u32 v = krow32[i];
    atomicAdd(&hist[(v >> 8) & 255u], 1u);
    atomicAdd(&hist[v >> 24], 1u);
  }
  __syncthreads();
  select_bin(K);
  const u32 b1 = s_sel; K = s_rem;

  // ---- pass 2: lo byte among hi-byte matches ----
  hist[tid] = 0; __syncthreads();
  for (int i = tid; i < NP2; i += 256) {
    u32 v = krow32[i];
    u32 lo = v & 0xFFFFu, hi = v >> 16;
    if ((lo >> 8) == b1) atomicAdd(&hist[lo & 255u], 1u);
    if ((hi >> 8) == b1) atomicAdd(&hist[hi & 255u], 1u);
  }
  __syncthreads();
  select_bin(K);
  const u32 pfx16 = (b1 << 8) | s_sel; K = s_rem;

  const bool fillMode = (pfx16 == NEGK16);
  u32 T;
  bool buffered = false;
  if (!fillMode) {
    // ---- pass 3: gather pfx16 matches w/ full keys into buf3; hist bits 15-8
    if (tid == 0) s_cnt3 = 0;
    hist[tid] = 0; __syncthreads();
    for (int i = tid; i < NP2; i += 256) {
      u32 v = krow32[i];
      u32 lo = v & 0xFFFFu, hi = v >> 16;
      if (lo == pfx16) {
        int p = 2 * i;
        u32 kf = fkey(loadscore(p));
        u32 slot = atomicAdd(&s_cnt3, 1u);
        if (slot < 512u) buf3[slot] = ((u64)kf << 32) | (u32)(~(u32)p);
        atomicAdd(&hist[(kf >> 8) & 255u], 1u);
      }
      if (hi == pfx16) {
        int p = 2 * i + 1;
        u32 kf = fkey(loadscore(p));
        u32 slot = atomicAdd(&s_cnt3, 1u);
        if (slot < 512u) buf3[slot] = ((u64)kf << 32) | (u32)(~(u32)p);
        atomicAdd(&hist[(kf >> 8) & 255u], 1u);
      }
    }
    __syncthreads();
    select_bin(K);
    const u32 b3 = s_sel; K = s_rem;
    buffered = (s_cnt3 <= 512u);  // uniform (shared), safe for barriers

    // ---- pass 4: low byte ----
    hist[tid] = 0; __syncthreads();
    if (buffered) {
      u32 n3 = s_cnt3;
      for (u32 i = tid; i < n3; i += 256) {
        u32 kf = (u32)(buf3[i] >> 32);
        if (((kf >> 8) & 255u) == b3) atomicAdd(&hist[kf & 255u], 1u);
      }
    } else {
      for (int i = tid; i < NP2; i += 256) {
        u32 v = krow32[i];
        u32 lo = v & 0xFFFFu, hi = v >> 16;
        if (lo == pfx16) {
          u32 kf = fkey(loadscore(2 * i));
          if (((kf >> 8) & 255u) == b3) atomicAdd(&hist[kf & 255u], 1u);
        }
        if (hi == pfx16) {
          u32 kf = fkey(loadscore(2 * i + 1));
          if (((kf >> 8) & 255u) == b3) atomicAdd(&hist[kf & 255u], 1u);
        }
      }
    }
    __syncthreads();
    select_bin(K);
    T = (pfx16 << 16) | (b3 << 8) | s_sel; K = s_rem;
  } else {
    T = NEGKEY;
  }

  // ---- gather G strictly-greater + ties ----
  const u32 G = TOPK - K;
  keys[tid] = 0;  // pad sorts last; only slots >= G+ties (>=200) stay pad
  if (tid == 0) { s_cnt = 0; s_cnt2 = 0; }
  __syncthreads();
  for (int i = tid; i < NP2; i += 256) {
    u32 v = krow32[i];
    u32 k16[2] = {v & 0xFFFFu, v >> 16};
#pragma unroll
    for (int h = 0; h < 2; ++h) {
      int p = 2 * i + h;
      if (k16[h] > pfx16) {
        u32 kf = fkey(loadscore(p));
        u32 slot = atomicAdd(&s_cnt, 1u);
        keys[slot] = ((u64)kf << 32) | (u32)(~(u32)p);
      } else if (!fillMode && !buffered && k16[h] == pfx16) {
        u32 kf = fkey(loadscore(p));
        if (kf > T) {
          u32 slot = atomicAdd(&s_cnt, 1u);
          keys[slot] = ((u64)kf << 32) | (u32)(~(u32)p);
        } else if (kf == T) {
          u32 t2 = atomicAdd(&s_cnt2, 1u);
          u32 slot = G + t2;
          if (slot < 256u) keys[slot] = ((u64)kf << 32) | (u32)(~(u32)p);
        }
      }
    }
  }
  if (buffered) {
    __syncthreads();  // buf3 stable already; order vs above writes is per-slot
    u32 n3 = s_cnt3;
    for (u32 i = tid; i < n3; i += 256) {
      u64 e = buf3[i];
      u32 kf = (u32)(e >> 32);
      if (kf > T) {
        u32 slot = atomicAdd(&s_cnt, 1u);
        keys[slot] = e;
      } else if (kf == T) {
        u32 t2 = atomicAdd(&s_cnt2, 1u);
        u32 slot = G + t2;
        if (slot < 256u) keys[slot] = e;
      }
    }
  }
  __syncthreads();
  if (fillMode) {  // inert filler entries (score -1, prior 0)
    for (int k = (int)G + tid; k < TOPK; k += 256)
      keys[k] = ((u64)T << 32) | 0xFFFFFFFFull;
    __syncthreads();
  }

  // ---- bitonic sort 256 u64 descending (score desc, prior asc via ~p) ----
  for (u32 kk = 2; kk <= 256; kk <<= 1) {
    for (u32 j = kk >> 1; j > 0; j >>= 1) {
      u32 ixj = (u32)tid ^ j;
      if (ixj > (u32)tid) {
        u64 a = keys[tid], bb = keys[ixj];
        bool asc = (tid & kk) != 0;
        if (asc ? (a > bb) : (a < bb)) { keys[tid] = bb; keys[ixj] = a; }
      }
      __syncthreads();
    }
  }

  // ---- decode 200 candidates (regs + LDS) ----
  float myscore = -1.f, rx0 = 0.f, ry0 = 0.f, rx1 = 0.f, ry1 = 0.f, rarea = 0.f;
  if (tid < TOPK) {
    u64 e = keys[tid];
    myscore = unfkey((u32)(e >> 32));
    int p = (int)(~(u32)e);
    const float* lp = loc + ((size_t)b * NP + p) * 4;
    const float* pp = prior + (size_t)p * 4;
    const float* vp = prior + (size_t)NP * 4 + (size_t)p * 4;
    float p0 = pp[0], p1 = pp[1], p2 = pp[2], p3 = pp[3];
    float pw = p2 - p0, ph = p3 - p1;
    float pcx = (p0 + p2) * 0.5f, pcy = (p1 + p3) * 0.5f;
    float cx = vp[0] * lp[0] * pw + pcx;
    float cy = vp[1] * lp[1] * ph + pcy;
    float w = expf(vp[2] * lp[2]) * pw;
    float h = expf(vp[3] * lp[3]) * ph;
    rx0 = cx - w * 0.5f; ry0 = cy - h * 0.5f;
    rx1 = cx + w * 0.5f; ry1 = cy + h * 0.5f;
    rarea = fmaxf(rx1 - rx0, 0.f) * fmaxf(ry1 - ry0, 0.f);
    bx0[tid] = rx0; bx1[tid] = ry0; bx2[tid] = rx1; bx3[tid] = ry1;
    barea[tid] = rarea;
    keepf[tid] = 0;
  }
  __syncthreads();

  // ---- greedy NMS, 1 barrier/iter (keepf[i] is the per-iter publish) ----
  int mysup = 0;
  for (int i = 0; i < TOPK; ++i) {
    if (tid == i) keepf[i] = (unsigned char)((myscore > CONF_THR) && !mysup);
    __syncthreads();
    if (keepf[i] && tid < TOPK) {
      float xx1 = fmaxf(bx0[i], rx0);
      float yy1 = fmaxf(bx1[i], ry0);
      float xx2 = fminf(bx2[i], rx1);
      float yy2 = fminf(bx3[i], ry1);
      float inter = fmaxf(xx2 - xx1, 0.f) * fmaxf(yy2 - yy1, 0.f);
      float uni = barea[i] + rarea - inter;
      float iou = inter / fmaxf(uni, 1e-10f);
      if (iou > NMS_THR) mysup = 1;
    }
  }
  __syncthreads();

  if (tid < TOPK) {
    kept[keptBase + tid] = keepf[tid] ? myscore : 0.f;
    float* bp = cbox + (keptBase + tid) * 4;
    bp[0] = rx0; bp[1] = ry0; bp[2] = rx1; bp[3] = ry1;
  }
}

// ---------------------------------------------------------------------------
// Kernel 1 (fallback, proven): strided scan version for small ws_size
// ---------------------------------------------------------------------------
__global__ __launch_bounds__(256) void perclass_fallback(
    const float* __restrict__ loc, const float* __restrict__ conf,
    const float* __restrict__ prior, float* __restrict__ kept,
    float* __restrict__ cbox) {
  __shared__ u16 skey[NP];
  __shared__ unsigned int hist[256];
  __shared__ u64 keys[256];
  __shared__ float bx0[TOPK], bx1[TOPK], bx2[TOPK], bx3[TOPK];
  __shared__ float barea[TOPK], bscore[TOPK];
  __shared__ unsigned char sup[TOPK], keepf[TOPK];
  __shared__ unsigned int s_sel, s_rem, s_cnt, s_cnt2;

  const int tid = threadIdx.x;
  const int nwg = NB * NCLS;
  int i0 = blockIdx.x;
  int bc = (i0 & 7) * (nwg / 8) + (i0 >> 3);
  const int b = bc / NCLS, c = bc % NCLS;
  const size_t keptBase = (size_t)bc * TOPK;

  if (c == 0) {
    for (int k = tid; k < TOPK; k += 256) {
      kept[keptBase + k] = 0.f;
      float* bp = cbox + (keptBase + k) * 4;
      bp[0] = 0.f; bp[1] = 0.f; bp[2] = 0.f; bp[3] = 0.f;
    }
    return;
  }

  const float* confb = conf + (size_t)b * NP * NCLS + c;
  auto loadscore = [&](int p) -> float {
    float s = confb[(size_t)p * NCLS];
    return (s > CONF_THR) ? s : -1.0f;
  };

  for (int p = tid; p < NP; p += 256)
    skey[p] = (u16)(fkey(loadscore(p)) >> 16);
  __syncthreads();

  auto select_bin = [&](u32 Kin) {
    if (tid == 0) {
      u32 rem = Kin;
      int bin = 255;
      for (; bin > 0; --bin) {
        u32 cnt = hist[bin];
        if (cnt >= rem) break;
        rem -= cnt;
      }
      s_sel = (u32)bin; s_rem = rem;
    }
    __syncthreads();
  };

  u32 K = TOPK;
  hist[tid] = 0; __syncthreads();
  for (int p = tid; p < NP; p += 256) atomicAdd(&hist[skey[p] >> 8], 1u);
  __syncthreads();
  select_bin(K);
  u32 pfx16 = s_sel << 8; K = s_rem;

  hist[tid] = 0; __syncthreads();
  {
    u32 hb = pfx16 >> 8;
    for (int p = tid; p < NP; p += 256) {
      u16 v = skey[p];
      if ((u32)(v >> 8) == hb) atomicAdd(&hist[v & 255], 1u);
    }
  }
  __syncthreads();
  select_bin(K);
  pfx16 |= s_sel; K = s_rem;

  const bool fillMode = (pfx16 == NEGK16);
  u32 T;
  if (!fillMode) {
    u32 pfull = pfx16 << 16;
    hist[tid] = 0; __syncthreads();
    for (int p = tid; p < NP; p += 256) {
      if ((u32)skey[p] == pfx16) {
        u32 kf = fkey(loadscore(p));
        atomicAdd(&hist[(kf >> 8) & 255], 1u);
      }
    }
    __syncthreads();
    select_bin(K);
    pfull |= s_sel << 8; K = s_rem;

    hist[tid] = 0; __syncthreads();
    for (int p = tid; p < NP; p += 256) {
      if ((u32)skey[p] == pfx16) {
        u32 kf = fkey(loadscore(p));
        if ((kf >> 8) == (pfull >> 8)) atomicAdd(&hist[kf & 255], 1u);
      }
    }
    __syncthreads();
    select_bin(K);
    T = pfull | s_sel; K = s_rem;
  } else {
    T = NEGKEY;
  }

  const u32 G = TOPK - K;
  keys[tid] = 0;
  if (tid == 0) { s_cnt = 0; s_cnt2 = 0; }
  __syncthreads();
  for (int p = tid; p < NP; p += 256) {
    u32 v = skey[p];
    if (v > pfx16) {
      float s = loadscore(p);
      u32 slot = atomicAdd(&s_cnt, 1u);
      keys[slot] = ((u64)fkey(s) << 32) | (u32)(~(u32)p);
    } else if (!fillMode && v == pfx16) {
      float s = loadscore(p);
      u32 kf = fkey(s);
      if (kf > T) {
        u32 slot = atomicAdd(&s_cnt, 1u);
        keys[slot] = ((u64)kf << 32) | (u32)(~(u32)p);
      } else if (kf == T) {
        u32 t2 = atomicAdd(&s_cnt2, 1u);
        u32 slot = G + t2;
        if (slot < 256u) keys[slot] = ((u64)kf << 32) | (u32)(~(u32)p);
      }
    }
  }
  __syncthreads();
  if (fillMode) {
    for (int k = (int)G + tid; k < TOPK; k += 256)
      keys[k] = ((u64)T << 32) | 0xFFFFFFFFull;
  }
  __syncthreads();

  for (u32 kk = 2; kk <= 256; kk <<= 1) {
    for (u32 j = kk >> 1; j > 0; j >>= 1) {
      u32 ixj = (u32)tid ^ j;
      if (ixj > (u32)tid) {
        u64 a = keys[tid], bb = keys[ixj];
        bool asc = (tid & kk) != 0;
        if (asc ? (a > bb) : (a < bb)) { keys[tid] = bb; keys[ixj] = a; }
      }
      __syncthreads();
    }
  }

  if (tid < TOPK) {
    u64 e = keys[tid];
    float s = unfkey((u32)(e >> 32));
    int p = (int)(~(u32)e);
    const float* lp = loc + ((size_t)b * NP + p) * 4;
    const float* pp = prior + (size_t)p * 4;
    const float* vp = prior + (size_t)NP * 4 + (size_t)p * 4;
    float p0 = pp[0], p1 = pp[1], p2 = pp[2], p3 = pp[3];
    float pw = p2 - p0, ph = p3 - p1;
    float pcx = (p0 + p2) * 0.5f, pcy = (p1 + p3) * 0.5f;
    float cx = vp[0] * lp[0] * pw + pcx;
    float cy = vp[1] * lp[1] * ph + pcy;
    float w = expf(vp[2] * lp[2]) * pw;
    float h = expf(vp[3] * lp[3]) * ph;
    float x0 = cx - w * 0.5f, y0 = cy - h * 0.5f;
    float x1 = cx + w * 0.5f, y1 = cy + h * 0.5f;
    bx0[tid] = x0; bx1[tid] = y0; bx2[tid] = x1; bx3[tid] = y1;
    barea[tid] = fmaxf(x1 - x0, 0.f) * fmaxf(y1 - y0, 0.f);
    bscore[tid] = s;
    sup[tid] = 0;
    keepf[tid] = 0;
  }
  __syncthreads();

  for (int i = 0; i < TOPK; ++i) {
    bool kept_i = (bscore[i] > CONF_THR) && (sup[i] == 0);
    __syncthreads();
    if (kept_i) {
      if (tid < TOPK) {
        float xx1 = fmaxf(bx0[i], bx0[tid]);
        float yy1 = fmaxf(bx1[i], bx1[tid]);
        float xx2 = fminf(bx2[i], bx2[tid]);
        float yy2 = fminf(bx3[i], bx3[tid]);
        float inter = fmaxf(xx2 - xx1, 0.f) * fmaxf(yy2 - yy1, 0.f);
        float uni = barea[i] + barea[tid] - inter;
        float iou = inter / fmaxf(uni, 1e-10f);
        if (iou > NMS_THR) sup[tid] = 1;
      }
      if (tid == 0) keepf[i] = 1;
    }
    __syncthreads();
  }

  if (tid < TOPK) {
    kept[keptBase + tid] = keepf[tid] ? bscore[tid] : 0.f;
    float* bp = cbox + (keptBase + tid) * 4;
    bp[0] = bx0[tid]; bp[1] = bx1[tid]; bp[2] = bx2[tid]; bp[3] = bx3[tid];
  }
}

// ---------------------------------------------------------------------------
// Kernel 2: per-batch top-200 over C*TOPK kept scores -> output rows
// ---------------------------------------------------------------------------
__global__ __launch_bounds__(256) void final_topk(
    const float* __restrict__ kept, const float* __restrict__ cbox,
    float* __restrict__ out) {
  __shared__ unsigned int hist[256];
  __shared__ u64 keys[256];
  __shared__ unsigned int s_sel, s_rem, s_cnt, s_cnt2;

  const int tid = threadIdx.x;
  const int b = blockIdx.x;
  const float* sc = kept + (size_t)b * NFLAT;

  auto select_bin = [&](u32 Kin) {
    if (tid == 0) {
      u32 rem = Kin;
      int bin = 255;
      for (; bin > 0; --bin) {
        u32 cnt = hist[bin];
        if (cnt >= rem) break;
        rem -= cnt;
      }
      s_sel = (u32)bin; s_rem = rem;
    }
    __syncthreads();
  };

  u32 pfx = 0;
  u32 K = KEEPK;
  for (int shift = 24; shift >= 0; shift -= 8) {
    hist[tid] = 0; __syncthreads();
    u32 himask = (shift == 24) ? 0u : (0xFFFFFFFFu << (shift + 8));
    for (int p = tid; p < NFLAT; p += 256) {
      u32 kf = fkey(sc[p]);
      if ((kf & himask) == pfx) atomicAdd(&hist[(kf >> shift) & 255], 1u);
    }
    __syncthreads();
    select_bin(K);
    pfx |= s_sel << shift; K = s_rem;
  }

  const bool fill2 = (pfx == fkey(0.0f));
  const u32 G = KEEPK - K;
  keys[tid] = 0;
  if (tid == 0) { s_cnt = 0; s_cnt2 = 0; }
  __syncthreads();
  for (int p = tid; p < NFLAT; p += 256) {
    u32 kf = fkey(sc[p]);
    if (kf > pfx) {
      u32 slot = atomicAdd(&s_cnt, 1u);
      keys[slot] = ((u64)kf << 32) | (u32)(~(u32)p);
    } else if (!fill2 && kf == pfx) {
      u32 t2 = atomicAdd(&s_cnt2, 1u);
      u32 slot = G + t2;
      if (slot < 256u) keys[slot] = ((u64)kf << 32) | (u32)(~(u32)p);
    }
  }
  __syncthreads();
  if (fill2) {
    for (int k = (int)G + tid; k < KEEPK; k += 256)
      keys[k] = ((u64)pfx << 32) | 0xFFFFFFFFull;
  }
  __syncthreads();

  for (u32 kk = 2; kk <= 256; kk <<= 1) {
    for (u32 j = kk >> 1; j > 0; j >>= 1) {
      u32 ixj = (u32)tid ^ j;
      if (ixj > (u32)tid) {
        u64 a = keys[tid], bb = keys[ixj];
        bool asc = (tid & kk) != 0;
        if (asc ? (a > bb) : (a < bb)) { keys[tid] = bb; keys[ixj] = a; }
      }
      __syncthreads();
    }
  }

  if (tid < KEEPK) {
    u64 e = keys[tid];
    float s = unfkey((u32)(e >> 32));
    u32 fi = ~(u32)e;
    float r0 = 0.f, r1 = 0.f, r2 = 0.f, r3 = 0.f, r4 = 0.f, r5 = 0.f, r6 = 0.f;
    if (s > 0.f) {
      r0 = (float)b;
      r1 = (float)(fi / TOPK);
      r2 = s;
      const float* bp = cbox + ((size_t)b * NFLAT + fi) * 4;
      r3 = bp[0]; r4 = bp[1]; r5 = bp[2]; r6 = bp[3];
    }
    float* op = out + ((size_t)b * KEEPK + tid) * 7;
    op[0] = r0; op[1] = r1; op[2] = r2; op[3] = r3;
    op[4] = r4; op[5] = r5; op[6] = r6;
  }
}

extern "C" void kernel_launch(void* const* d_in, const int* in_sizes, int n_in,
                              void* d_out, int out_size, void* d_ws, size_t ws_size,
                              hipStream_t stream) {
  const float* loc = (const float*)d_in[0];
  const float* conf = (const float*)d_in[1];
  const float* prior = (const float*)d_in[2];
  float* out = (float*)d_out;

  float* kept = (float*)d_ws;                     // NB*NCLS*TOPK floats
  float* cbox = kept + (size_t)NB * NCLS * TOPK;  // NB*NCLS*TOPK*4 floats
  const size_t baseBytes = (size_t)NB * NCLS * TOPK * 5 * sizeof(float);  // 10.37 MB
  const size_t keysBytes = (size_t)NB * NCLS * NP * sizeof(u16);          // 127.3 MB

  if (ws_size >= baseBytes + keysBytes) {
    u16* keys16 = (u16*)((char*)d_ws + baseBytes);
    build_keys<<<dim3(NB * NCHUNK), dim3(256), 0, stream>>>(conf, keys16);
    perclass_v2<<<dim3(NB * NCLS), dim3(256), 0, stream>>>(loc, conf, prior,
                                                           keys16, kept, cbox);
  } else {
    perclass_fallback<<<dim3(NB * NCLS), dim3(256), 0, stream>>>(loc, conf,
                                                                 prior, kept, cbox);
  }
  final_topk<<<dim3(NB), dim3(256), 0, stream>>>(kept, cbox, out);
}